// Round 1
// baseline (1588.198 us; speedup 1.0000x reference)
//
#include <hip/hip_runtime.h>

#define N_NODES 50000
#define D_IN    128
#define D_H     256
#define MT      16
#define NB      (N_NODES / MT)   // 3125 exact, no tail

// ---------------------------------------------------------------- init: h = (1+eps)*x
__global__ __launch_bounds__(256) void init_h_kernel(const float* __restrict__ x,
                                                     const float* __restrict__ eps,
                                                     float* __restrict__ h, int total4) {
    int i = blockIdx.x * 256 + threadIdx.x;
    if (i >= total4) return;
    float s = 1.0f + eps[0];
    float4 v = ((const float4*)x)[i];
    v.x *= s; v.y *= s; v.z *= s; v.w *= s;
    ((float4*)h)[i] = v;
}

// ---------------------------------------------------------------- scatter: h[dst] += x[src]
// thread t -> edge e = t/32, chunk c = t%32 (4 floats). Lanes 0..31 cover one
// edge's 512B row: coalesced gather + contiguous atomics.
__global__ __launch_bounds__(256) void scatter_kernel(const float* __restrict__ x,
                                                      const int* __restrict__ ei,
                                                      float* __restrict__ h, int E) {
    int t = blockIdx.x * 256 + threadIdx.x;
    int e = t >> 5;
    if (e >= E) return;
    int c = (t & 31) << 2;
    int src = ei[e];
    int dst = ei[E + e];
    float4 v = *(const float4*)(x + (size_t)src * D_IN + c);
    float* p = h + (size_t)dst * D_IN + c;
    unsafeAtomicAdd(p + 0, v.x);
    unsafeAtomicAdd(p + 1, v.y);
    unsafeAtomicAdd(p + 2, v.z);
    unsafeAtomicAdd(p + 3, v.w);
}

// ---------------------------------------------------------------- GEMM1: h1 = h @ W1, + BN1 partial stats
__global__ __launch_bounds__(256) void gemm1_kernel(const float* __restrict__ h,
                                                    const float* __restrict__ W1,
                                                    float* __restrict__ h1,
                                                    float* __restrict__ partial) {
    __shared__ float a[MT][D_IN];
    int tid = threadIdx.x;             // == output column n
    int row0 = blockIdx.x * MT;
    // stage 16x128 tile (512 float4, 2 per thread), coalesced
    for (int i = tid; i < MT * D_IN / 4; i += 256) {
        int r = i >> 5, c = (i & 31) << 2;
        *(float4*)&a[r][c] = *(const float4*)(h + (size_t)(row0 + r) * D_IN + c);
    }
    __syncthreads();
    float acc[MT];
#pragma unroll
    for (int r = 0; r < MT; r++) acc[r] = 0.f;
    for (int k = 0; k < D_IN; k += 4) {
        float w0 = W1[(k + 0) * D_H + tid];
        float w1 = W1[(k + 1) * D_H + tid];
        float w2 = W1[(k + 2) * D_H + tid];
        float w3 = W1[(k + 3) * D_H + tid];
#pragma unroll
        for (int r = 0; r < MT; r++) {
            float4 av = *(const float4*)&a[r][k];   // wave-uniform broadcast read
            acc[r] = fmaf(av.x, w0, acc[r]);
            acc[r] = fmaf(av.y, w1, acc[r]);
            acc[r] = fmaf(av.z, w2, acc[r]);
            acc[r] = fmaf(av.w, w3, acc[r]);
        }
    }
    float s = 0.f, ss = 0.f;
#pragma unroll
    for (int r = 0; r < MT; r++) {
        float v = acc[r];
        h1[(size_t)(row0 + r) * D_H + tid] = v;
        s += v;
        ss = fmaf(v, v, ss);
    }
    // per-block partial sums, coalesced store: [block][2*256]
    partial[(size_t)blockIdx.x * (2 * D_H) + tid] = s;
    partial[(size_t)blockIdx.x * (2 * D_H) + D_H + tid] = ss;
}

// ---------------------------------------------------------------- BN finalize: per-feature scale/shift
__global__ __launch_bounds__(256) void bn_finalize_kernel(const float* __restrict__ partial,
                                                          const float* __restrict__ gamma,
                                                          const float* __restrict__ beta,
                                                          float* __restrict__ scale,
                                                          float* __restrict__ shift) {
    int s = blockIdx.x;        // feature 0..255
    int tid = threadIdx.x;
    float sum = 0.f, sq = 0.f;
    for (int b = tid; b < NB; b += 256) {
        sum += partial[(size_t)b * (2 * D_H) + s];
        sq  += partial[(size_t)b * (2 * D_H) + D_H + s];
    }
    __shared__ float rs[256], rq[256];
    rs[tid] = sum; rq[tid] = sq;
    __syncthreads();
    for (int off = 128; off > 0; off >>= 1) {
        if (tid < off) { rs[tid] += rs[tid + off]; rq[tid] += rq[tid + off]; }
        __syncthreads();
    }
    if (tid == 0) {
        float inv  = 1.0f / (float)N_NODES;
        float mean = rs[0] * inv;
        float var  = rq[0] * inv - mean * mean;
        float sc   = gamma[s] * rsqrtf(var + 1e-5f);
        scale[s] = sc;
        shift[s] = fmaf(-mean, sc, beta[s]);
    }
}

// ---------------------------------------------------------------- GEMM2: h2 = relu(BN1(h1)) @ W2, + BN2 stats
__global__ __launch_bounds__(256) void gemm2_kernel(const float* __restrict__ h1,
                                                    const float* __restrict__ W2,
                                                    const float* __restrict__ scale1,
                                                    const float* __restrict__ shift1,
                                                    float* __restrict__ h2,
                                                    float* __restrict__ partial) {
    __shared__ float a[MT][D_H];
    int tid = threadIdx.x;
    int row0 = blockIdx.x * MT;
    // stage 16x256 tile, applying BN1 + ReLU on load
    for (int i = tid; i < MT * D_H / 4; i += 256) {
        int r = i >> 6, c = (i & 63) << 2;
        float4 v  = *(const float4*)(h1 + (size_t)(row0 + r) * D_H + c);
        float4 sc = *(const float4*)(scale1 + c);
        float4 sh = *(const float4*)(shift1 + c);
        v.x = fmaxf(fmaf(v.x, sc.x, sh.x), 0.f);
        v.y = fmaxf(fmaf(v.y, sc.y, sh.y), 0.f);
        v.z = fmaxf(fmaf(v.z, sc.z, sh.z), 0.f);
        v.w = fmaxf(fmaf(v.w, sc.w, sh.w), 0.f);
        *(float4*)&a[r][c] = v;
    }
    __syncthreads();
    float acc[MT];
#pragma unroll
    for (int r = 0; r < MT; r++) acc[r] = 0.f;
    for (int k = 0; k < D_H; k += 4) {
        float w0 = W2[(k + 0) * D_H + tid];
        float w1 = W2[(k + 1) * D_H + tid];
        float w2 = W2[(k + 2) * D_H + tid];
        float w3 = W2[(k + 3) * D_H + tid];
#pragma unroll
        for (int r = 0; r < MT; r++) {
            float4 av = *(const float4*)&a[r][k];
            acc[r] = fmaf(av.x, w0, acc[r]);
            acc[r] = fmaf(av.y, w1, acc[r]);
            acc[r] = fmaf(av.z, w2, acc[r]);
            acc[r] = fmaf(av.w, w3, acc[r]);
        }
    }
    float s = 0.f, ss = 0.f;
#pragma unroll
    for (int r = 0; r < MT; r++) {
        float v = acc[r];
        h2[(size_t)(row0 + r) * D_H + tid] = v;
        s += v;
        ss = fmaf(v, v, ss);
    }
    partial[(size_t)blockIdx.x * (2 * D_H) + tid] = s;
    partial[(size_t)blockIdx.x * (2 * D_H) + D_H + tid] = ss;
}

// ---------------------------------------------------------------- final: out = relu(BN2(h2)) in place
__global__ __launch_bounds__(256) void bn2_apply_kernel(float* __restrict__ out,
                                                        const float* __restrict__ scale,
                                                        const float* __restrict__ shift,
                                                        int total4) {
    int i = blockIdx.x * 256 + threadIdx.x;
    if (i >= total4) return;
    float4 v = ((float4*)out)[i];
    int c = (i & 63) << 2;     // column group (row = 256 floats = 64 float4)
    float4 sc = *(const float4*)(scale + c);
    float4 sh = *(const float4*)(shift + c);
    v.x = fmaxf(fmaf(v.x, sc.x, sh.x), 0.f);
    v.y = fmaxf(fmaf(v.y, sc.y, sh.y), 0.f);
    v.z = fmaxf(fmaf(v.z, sc.z, sh.z), 0.f);
    v.w = fmaxf(fmaf(v.w, sc.w, sh.w), 0.f);
    ((float4*)out)[i] = v;
}

// ----------------------------------------------------------------
extern "C" void kernel_launch(void* const* d_in, const int* in_sizes, int n_in,
                              void* d_out, int out_size, void* d_ws, size_t ws_size,
                              hipStream_t stream) {
    const float* x      = (const float*)d_in[0];
    const int*   ei     = (const int*)d_in[1];   // [2][E] int32
    const float* eps    = (const float*)d_in[3];
    const float* W1     = (const float*)d_in[4];
    const float* gamma1 = (const float*)d_in[5];
    const float* beta1  = (const float*)d_in[6];
    const float* W2     = (const float*)d_in[7];
    const float* gamma2 = (const float*)d_in[8];
    const float* beta2  = (const float*)d_in[9];
    int E = in_sizes[1] / 2;

    char* ws = (char*)d_ws;
    float* h       = (float*)(ws);                 // 50000*128*4 = 25,600,000 B
    float* h1      = (float*)(ws + 25600000);      // 50000*256*4 = 51,200,000 B
    float* partial = (float*)(ws + 76800000);      // 3125*512*4  =  6,400,000 B
    float* stats   = (float*)(ws + 83200000);      // 4*256*4 B
    float* scale1 = stats, *shift1 = stats + 256, *scale2 = stats + 512, *shift2 = stats + 768;
    float* out = (float*)d_out;

    init_h_kernel<<<(N_NODES * D_IN / 4 + 255) / 256, 256, 0, stream>>>(x, eps, h, N_NODES * D_IN / 4);
    scatter_kernel<<<(E * 32 + 255) / 256, 256, 0, stream>>>(x, ei, h, E);
    gemm1_kernel<<<NB, 256, 0, stream>>>(h, W1, h1, partial);
    bn_finalize_kernel<<<D_H, 256, 0, stream>>>(partial, gamma1, beta1, scale1, shift1);
    gemm2_kernel<<<NB, 256, 0, stream>>>(h1, W2, scale1, shift1, out, partial);
    bn_finalize_kernel<<<D_H, 256, 0, stream>>>(partial, gamma2, beta2, scale2, shift2);
    bn2_apply_kernel<<<(N_NODES * D_H / 4 + 255) / 256, 256, 0, stream>>>(out, scale2, shift2, N_NODES * D_H / 4);
}

// Round 3
// 390.904 us; speedup vs baseline: 4.0629x; 4.0629x over previous
//
#include <hip/hip_runtime.h>

#define N_NODES 50000
#define D_IN    128
#define D_H     256
#define MT      16
#define NB      (N_NODES / MT)           // 3125 exact, no tail
#define SCAN_BLK ((N_NODES + 255) / 256) // 196

// ================================================================ aggregation (sort-based)

// ---- histogram of dst
__global__ __launch_bounds__(256) void hist_kernel(const int* __restrict__ ei, int* __restrict__ count, int E) {
    int e = blockIdx.x * 256 + threadIdx.x;
    if (e >= E) return;
    atomicAdd(&count[ei[E + e]], 1);
}

// ---- block-local exclusive scan of count -> offset (no base), block totals -> bsum
__global__ __launch_bounds__(256) void scan_blocks_kernel(const int* __restrict__ count,
                                                          int* __restrict__ offset,
                                                          int* __restrict__ bsum) {
    __shared__ int sh[256];
    int tid = threadIdx.x;
    int i = blockIdx.x * 256 + tid;
    int v = (i < N_NODES) ? count[i] : 0;
    sh[tid] = v;
    __syncthreads();
    for (int off = 1; off < 256; off <<= 1) {
        int t = (tid >= off) ? sh[tid - off] : 0;
        __syncthreads();
        sh[tid] += t;
        __syncthreads();
    }
    if (i < N_NODES) offset[i] = sh[tid] - v;  // exclusive
    if (tid == 255) bsum[blockIdx.x] = sh[255];
}

// ---- exclusive scan of the 196 block sums (single block)
__global__ __launch_bounds__(256) void scan_bsum_kernel(int* __restrict__ bsum) {
    __shared__ int sh[256];
    int tid = threadIdx.x;
    int v = (tid < SCAN_BLK) ? bsum[tid] : 0;
    sh[tid] = v;
    __syncthreads();
    for (int off = 1; off < 256; off <<= 1) {
        int t = (tid >= off) ? sh[tid - off] : 0;
        __syncthreads();
        sh[tid] += t;
        __syncthreads();
    }
    if (tid < SCAN_BLK) bsum[tid] = sh[tid] - v;
}

// ---- add block bases
__global__ __launch_bounds__(256) void add_base_kernel(int* __restrict__ offset, const int* __restrict__ bsum) {
    int i = blockIdx.x * 256 + threadIdx.x;
    if (i < N_NODES) offset[i] += bsum[blockIdx.x];
}

// ---- scatter src indices into dst-sorted order
__global__ __launch_bounds__(256) void fill_kernel(const int* __restrict__ ei,
                                                   const int* __restrict__ offset,
                                                   int* __restrict__ fill,
                                                   int* __restrict__ sorted_src, int E) {
    int e = blockIdx.x * 256 + threadIdx.x;
    if (e >= E) return;
    int src = ei[e];
    int dst = ei[E + e];
    int pos = offset[dst] + atomicAdd(&fill[dst], 1);
    sorted_src[pos] = src;
}

// ---- gather-sum: h[d] = (1+eps)*x[d] + sum_{src in adj(d)} x[src]
// 8 nodes per block; 32-lane group per node, lane owns 4 floats of the row.
__global__ __launch_bounds__(256) void gather_kernel(const float* __restrict__ x,
                                                     const float* __restrict__ eps,
                                                     const int* __restrict__ offset,
                                                     const int* __restrict__ count,
                                                     const int* __restrict__ sorted_src,
                                                     float* __restrict__ h) {
    int g = threadIdx.x >> 5, lane = threadIdx.x & 31;
    int d = blockIdx.x * 8 + g;
    if (d >= N_NODES) return;
    int c = lane << 2;
    float s = 1.0f + eps[0];
    float4 acc = *(const float4*)(x + (size_t)d * D_IN + c);
    acc.x *= s; acc.y *= s; acc.z *= s; acc.w *= s;
    int beg = offset[d], cnt = count[d];
    int j = 0;
    for (; j + 1 < cnt; j += 2) {          // 2-deep MLP per lane
        int s0 = sorted_src[beg + j];
        int s1 = sorted_src[beg + j + 1];
        float4 v0 = *(const float4*)(x + (size_t)s0 * D_IN + c);
        float4 v1 = *(const float4*)(x + (size_t)s1 * D_IN + c);
        acc.x += v0.x + v1.x; acc.y += v0.y + v1.y;
        acc.z += v0.z + v1.z; acc.w += v0.w + v1.w;
    }
    if (j < cnt) {
        int s0 = sorted_src[beg + j];
        float4 v0 = *(const float4*)(x + (size_t)s0 * D_IN + c);
        acc.x += v0.x; acc.y += v0.y; acc.z += v0.z; acc.w += v0.w;
    }
    *(float4*)(h + (size_t)d * D_IN + c) = acc;
}

// ================================================================ GEMM1: h1 = h @ W1, + BN1 partial stats
__global__ __launch_bounds__(256) void gemm1_kernel(const float* __restrict__ h,
                                                    const float* __restrict__ W1,
                                                    float* __restrict__ h1,
                                                    float* __restrict__ partial) {
    __shared__ float a[MT][D_IN];
    int tid = threadIdx.x;             // == output column n
    int row0 = blockIdx.x * MT;
    for (int i = tid; i < MT * D_IN / 4; i += 256) {
        int r = i >> 5, c = (i & 31) << 2;
        *(float4*)&a[r][c] = *(const float4*)(h + (size_t)(row0 + r) * D_IN + c);
    }
    __syncthreads();
    float acc[MT];
#pragma unroll
    for (int r = 0; r < MT; r++) acc[r] = 0.f;
    for (int k = 0; k < D_IN; k += 4) {
        float w0 = W1[(k + 0) * D_H + tid];
        float w1 = W1[(k + 1) * D_H + tid];
        float w2 = W1[(k + 2) * D_H + tid];
        float w3 = W1[(k + 3) * D_H + tid];
#pragma unroll
        for (int r = 0; r < MT; r++) {
            float4 av = *(const float4*)&a[r][k];
            acc[r] = fmaf(av.x, w0, acc[r]);
            acc[r] = fmaf(av.y, w1, acc[r]);
            acc[r] = fmaf(av.z, w2, acc[r]);
            acc[r] = fmaf(av.w, w3, acc[r]);
        }
    }
    float s = 0.f, ss = 0.f;
#pragma unroll
    for (int r = 0; r < MT; r++) {
        float v = acc[r];
        h1[(size_t)(row0 + r) * D_H + tid] = v;
        s += v;
        ss = fmaf(v, v, ss);
    }
    partial[(size_t)blockIdx.x * (2 * D_H) + tid] = s;
    partial[(size_t)blockIdx.x * (2 * D_H) + D_H + tid] = ss;
}

// ================================================================ BN finalize
__global__ __launch_bounds__(256) void bn_finalize_kernel(const float* __restrict__ partial,
                                                          const float* __restrict__ gamma,
                                                          const float* __restrict__ beta,
                                                          float* __restrict__ scale,
                                                          float* __restrict__ shift) {
    int s = blockIdx.x;
    int tid = threadIdx.x;
    float sum = 0.f, sq = 0.f;
    for (int b = tid; b < NB; b += 256) {
        sum += partial[(size_t)b * (2 * D_H) + s];
        sq  += partial[(size_t)b * (2 * D_H) + D_H + s];
    }
    __shared__ float rs[256], rq[256];
    rs[tid] = sum; rq[tid] = sq;
    __syncthreads();
    for (int off = 128; off > 0; off >>= 1) {
        if (tid < off) { rs[tid] += rs[tid + off]; rq[tid] += rq[tid + off]; }
        __syncthreads();
    }
    if (tid == 0) {
        float inv  = 1.0f / (float)N_NODES;
        float mean = rs[0] * inv;
        float var  = rq[0] * inv - mean * mean;
        float sc   = gamma[s] * rsqrtf(var + 1e-5f);
        scale[s] = sc;
        shift[s] = fmaf(-mean, sc, beta[s]);
    }
}

// ================================================================ GEMM2: h2 = relu(BN1(h1)) @ W2, + BN2 stats
__global__ __launch_bounds__(256) void gemm2_kernel(const float* __restrict__ h1,
                                                    const float* __restrict__ W2,
                                                    const float* __restrict__ scale1,
                                                    const float* __restrict__ shift1,
                                                    float* __restrict__ h2,
                                                    float* __restrict__ partial) {
    __shared__ float a[MT][D_H];
    int tid = threadIdx.x;
    int row0 = blockIdx.x * MT;
    for (int i = tid; i < MT * D_H / 4; i += 256) {
        int r = i >> 6, c = (i & 63) << 2;
        float4 v  = *(const float4*)(h1 + (size_t)(row0 + r) * D_H + c);
        float4 sc = *(const float4*)(scale1 + c);
        float4 sh = *(const float4*)(shift1 + c);
        v.x = fmaxf(fmaf(v.x, sc.x, sh.x), 0.f);
        v.y = fmaxf(fmaf(v.y, sc.y, sh.y), 0.f);
        v.z = fmaxf(fmaf(v.z, sc.z, sh.z), 0.f);
        v.w = fmaxf(fmaf(v.w, sc.w, sh.w), 0.f);
        *(float4*)&a[r][c] = v;
    }
    __syncthreads();
    float acc[MT];
#pragma unroll
    for (int r = 0; r < MT; r++) acc[r] = 0.f;
    for (int k = 0; k < D_H; k += 4) {
        float w0 = W2[(k + 0) * D_H + tid];
        float w1 = W2[(k + 1) * D_H + tid];
        float w2 = W2[(k + 2) * D_H + tid];
        float w3 = W2[(k + 3) * D_H + tid];
#pragma unroll
        for (int r = 0; r < MT; r++) {
            float4 av = *(const float4*)&a[r][k];
            acc[r] = fmaf(av.x, w0, acc[r]);
            acc[r] = fmaf(av.y, w1, acc[r]);
            acc[r] = fmaf(av.z, w2, acc[r]);
            acc[r] = fmaf(av.w, w3, acc[r]);
        }
    }
    float s = 0.f, ss = 0.f;
#pragma unroll
    for (int r = 0; r < MT; r++) {
        float v = acc[r];
        h2[(size_t)(row0 + r) * D_H + tid] = v;
        s += v;
        ss = fmaf(v, v, ss);
    }
    partial[(size_t)blockIdx.x * (2 * D_H) + tid] = s;
    partial[(size_t)blockIdx.x * (2 * D_H) + D_H + tid] = ss;
}

// ================================================================ final: out = relu(BN2(h2)) in place
__global__ __launch_bounds__(256) void bn2_apply_kernel(float* __restrict__ out,
                                                        const float* __restrict__ scale,
                                                        const float* __restrict__ shift,
                                                        int total4) {
    int i = blockIdx.x * 256 + threadIdx.x;
    if (i >= total4) return;
    float4 v = ((float4*)out)[i];
    int c = (i & 63) << 2;
    float4 sc = *(const float4*)(scale + c);
    float4 sh = *(const float4*)(shift + c);
    v.x = fmaxf(fmaf(v.x, sc.x, sh.x), 0.f);
    v.y = fmaxf(fmaf(v.y, sc.y, sh.y), 0.f);
    v.z = fmaxf(fmaf(v.z, sc.z, sh.z), 0.f);
    v.w = fmaxf(fmaf(v.w, sc.w, sh.w), 0.f);
    ((float4*)out)[i] = v;
}

// ================================================================
extern "C" void kernel_launch(void* const* d_in, const int* in_sizes, int n_in,
                              void* d_out, int out_size, void* d_ws, size_t ws_size,
                              hipStream_t stream) {
    const float* x      = (const float*)d_in[0];
    const int*   ei     = (const int*)d_in[1];   // [2][E] int32
    const float* eps    = (const float*)d_in[3];
    const float* W1     = (const float*)d_in[4];
    const float* gamma1 = (const float*)d_in[5];
    const float* beta1  = (const float*)d_in[6];
    const float* W2     = (const float*)d_in[7];
    const float* gamma2 = (const float*)d_in[8];
    const float* beta2  = (const float*)d_in[9];
    int E = in_sizes[1] / 2;

    char* ws = (char*)d_ws;
    float* h       = (float*)(ws);                 // 25,600,000 B
    float* h1      = (float*)(ws + 25600000);      // 51,200,000 B (also sort scratch, pre-gemm1)
    float* partial = (float*)(ws + 76800000);      //  6,400,000 B
    float* stats   = (float*)(ws + 83200000);      //  4 KB
    float* scale1 = stats, *shift1 = stats + 256, *scale2 = stats + 512, *shift2 = stats + 768;
    float* out = (float*)d_out;

    // sort scratch overlapping h1 (dead until gemm1)
    char* sb = (char*)h1;
    int* count      = (int*)(sb);                  // 200,000 B
    int* offset     = (int*)(sb + 200064);         // 200,064 B
    int* fill       = (int*)(sb + 400128);         // 200,000 B
    int* bsum       = (int*)(sb + 600192);         //   1,024 B
    int* sorted_src = (int*)(sb + 601216);         // 4*E B

    hipMemsetAsync(count, 0, N_NODES * sizeof(int), stream);
    hipMemsetAsync(fill,  0, N_NODES * sizeof(int), stream);

    int eblk = (E + 255) / 256;
    hist_kernel<<<eblk, 256, 0, stream>>>(ei, count, E);
    scan_blocks_kernel<<<SCAN_BLK, 256, 0, stream>>>(count, offset, bsum);
    scan_bsum_kernel<<<1, 256, 0, stream>>>(bsum);
    add_base_kernel<<<SCAN_BLK, 256, 0, stream>>>(offset, bsum);
    fill_kernel<<<eblk, 256, 0, stream>>>(ei, offset, fill, sorted_src, E);
    gather_kernel<<<(N_NODES + 7) / 8, 256, 0, stream>>>(x, eps, offset, count, sorted_src, h);

    gemm1_kernel<<<NB, 256, 0, stream>>>(h, W1, h1, partial);
    bn_finalize_kernel<<<D_H, 256, 0, stream>>>(partial, gamma1, beta1, scale1, shift1);
    gemm2_kernel<<<NB, 256, 0, stream>>>(h1, W2, scale1, shift1, out, partial);
    bn_finalize_kernel<<<D_H, 256, 0, stream>>>(partial, gamma2, beta2, scale2, shift2);
    bn2_apply_kernel<<<(N_NODES * D_H / 4 + 255) / 256, 256, 0, stream>>>(out, scale2, shift2, N_NODES * D_H / 4);
}

// Round 5
// 240.357 us; speedup vs baseline: 6.6077x; 1.6263x over previous
//
#include <hip/hip_runtime.h>

#define N_NODES 50000
#define D_IN    128
#define D_H     256
#define MT      16
#define NB      (N_NODES / MT)           // 3125 exact, no tail
#define SCAN_BLK ((N_NODES + 255) / 256) // 196

typedef short s16x8 __attribute__((ext_vector_type(8)));
typedef short s16x4 __attribute__((ext_vector_type(4)));
typedef float f32x4 __attribute__((ext_vector_type(4)));

__device__ inline ushort f2bf(float f) {           // RNE fp32->bf16
    uint u = __float_as_uint(f);
    return (ushort)((u + 0x7FFFu + ((u >> 16) & 1u)) >> 16);
}

// ================================================================ aggregation (sort-based)

__global__ __launch_bounds__(256) void hist_kernel(const int* __restrict__ ei, int* __restrict__ count, int E) {
    int e = blockIdx.x * 256 + threadIdx.x;
    if (e >= E) return;
    atomicAdd(&count[ei[E + e]], 1);
}

__global__ __launch_bounds__(256) void scan_blocks_kernel(const int* __restrict__ count,
                                                          int* __restrict__ offset,
                                                          int* __restrict__ bsum) {
    __shared__ int sh[256];
    int tid = threadIdx.x;
    int i = blockIdx.x * 256 + tid;
    int v = (i < N_NODES) ? count[i] : 0;
    sh[tid] = v;
    __syncthreads();
    for (int off = 1; off < 256; off <<= 1) {
        int t = (tid >= off) ? sh[tid - off] : 0;
        __syncthreads();
        sh[tid] += t;
        __syncthreads();
    }
    if (i < N_NODES) offset[i] = sh[tid] - v;
    if (tid == 255) bsum[blockIdx.x] = sh[255];
}

__global__ __launch_bounds__(256) void scan_bsum_kernel(int* __restrict__ bsum) {
    __shared__ int sh[256];
    int tid = threadIdx.x;
    int v = (tid < SCAN_BLK) ? bsum[tid] : 0;
    sh[tid] = v;
    __syncthreads();
    for (int off = 1; off < 256; off <<= 1) {
        int t = (tid >= off) ? sh[tid - off] : 0;
        __syncthreads();
        sh[tid] += t;
        __syncthreads();
    }
    if (tid < SCAN_BLK) bsum[tid] = sh[tid] - v;
}

__global__ __launch_bounds__(256) void add_base_kernel(int* __restrict__ offset, const int* __restrict__ bsum) {
    int i = blockIdx.x * 256 + threadIdx.x;
    if (i < N_NODES) offset[i] += bsum[blockIdx.x];
}

__global__ __launch_bounds__(256) void fill_kernel(const int* __restrict__ ei,
                                                   const int* __restrict__ offset,
                                                   int* __restrict__ fill,
                                                   int* __restrict__ sorted_src, int E) {
    int e = blockIdx.x * 256 + threadIdx.x;
    if (e >= E) return;
    int src = ei[e];
    int dst = ei[E + e];
    int pos = offset[dst] + atomicAdd(&fill[dst], 1);
    sorted_src[pos] = src;
}

// gather-sum -> bf16 h
__global__ __launch_bounds__(256) void gather_kernel(const float* __restrict__ x,
                                                     const float* __restrict__ eps,
                                                     const int* __restrict__ offset,
                                                     const int* __restrict__ count,
                                                     const int* __restrict__ sorted_src,
                                                     ushort* __restrict__ h) {
    int g = threadIdx.x >> 5, lane = threadIdx.x & 31;
    int d = blockIdx.x * 8 + g;
    if (d >= N_NODES) return;
    int c = lane << 2;
    float s = 1.0f + eps[0];
    float4 acc = *(const float4*)(x + (size_t)d * D_IN + c);
    acc.x *= s; acc.y *= s; acc.z *= s; acc.w *= s;
    int beg = offset[d], cnt = count[d];
    int j = 0;
    for (; j + 1 < cnt; j += 2) {
        int s0 = sorted_src[beg + j];
        int s1 = sorted_src[beg + j + 1];
        float4 v0 = *(const float4*)(x + (size_t)s0 * D_IN + c);
        float4 v1 = *(const float4*)(x + (size_t)s1 * D_IN + c);
        acc.x += v0.x + v1.x; acc.y += v0.y + v1.y;
        acc.z += v0.z + v1.z; acc.w += v0.w + v1.w;
    }
    if (j < cnt) {
        int s0 = sorted_src[beg + j];
        float4 v0 = *(const float4*)(x + (size_t)s0 * D_IN + c);
        acc.x += v0.x; acc.y += v0.y; acc.z += v0.z; acc.w += v0.w;
    }
    s16x4 o;
    o[0] = (short)f2bf(acc.x); o[1] = (short)f2bf(acc.y);
    o[2] = (short)f2bf(acc.z); o[3] = (short)f2bf(acc.w);
    *(s16x4*)(h + (size_t)d * D_IN + c) = o;
}

// ================================================================ W pack: fragment-order bf16
// unit u = (s*16+g)*64 + lane; elem j -> W[k = s*32 + (lane>>4)*8 + j][g*16 + (lane&15)]
__global__ __launch_bounds__(256) void pack_w_kernel(const float* __restrict__ W1,
                                                     const float* __restrict__ W2,
                                                     ushort* __restrict__ Wp1,
                                                     ushort* __restrict__ Wp2) {
    int t = blockIdx.x * 256 + threadIdx.x;
    const float* W; ushort* Wp; int u;
    if (t < 4096)       { W = W1; Wp = Wp1; u = t; }          // 4 ksteps * 16 g * 64
    else if (t < 12288) { W = W2; Wp = Wp2; u = t - 4096; }   // 8 ksteps * 16 g * 64
    else return;
    int l = u & 63, gs = u >> 6;
    int g = gs & 15, s = gs >> 4;
    int col = g * 16 + (l & 15), q = l >> 4;
    s16x8 o;
#pragma unroll
    for (int j = 0; j < 8; j++) {
        int k = s * 32 + q * 8 + j;
        o[j] = (short)f2bf(W[(size_t)k * D_H + col]);
    }
    *(s16x8*)(Wp + (size_t)u * 8) = o;
}

// ================================================================ GEMM1 (MFMA): h1 = h @ W1 + BN1 stats
__global__ __launch_bounds__(256) void gemm1_kernel(const ushort* __restrict__ hB,
                                                    const ushort* __restrict__ Wp,
                                                    float* __restrict__ h1,
                                                    float* __restrict__ partial) {
    __shared__ ushort A[MT * D_IN];   // 16x128 bf16, XOR-swizzled rows (stride 256 B)
    int tid = threadIdx.x, lane = tid & 63, w = tid >> 6;
    int row0 = blockIdx.x * MT;
    {
        int r = tid >> 4, cb = (tid & 15) << 4;    // byte col within 256-B row
        s16x8 v = *(const s16x8*)(hB + (size_t)(row0 + r) * D_IN + (cb >> 1));
        *(s16x8*)((char*)A + r * 256 + (cb ^ ((r & 7) << 4))) = v;
    }
    __syncthreads();
    int m = lane & 15, q = lane >> 4;
    int sw = (m & 7) << 4;
    f32x4 acc[4] = {};
    const s16x8* B = (const s16x8*)Wp;
#pragma unroll
    for (int s = 0; s < 4; s++) {
        s16x8 a = *(const s16x8*)((char*)A + m * 256 + ((s * 64 + q * 16) ^ sw));
#pragma unroll
        for (int f = 0; f < 4; f++) {
            int g = w * 4 + f;
            s16x8 b = B[(s * 16 + g) * 64 + lane];
            acc[f] = __builtin_amdgcn_mfma_f32_16x16x32_bf16(a, b, acc[f], 0, 0, 0);
        }
    }
#pragma unroll
    for (int f = 0; f < 4; f++) {
        int g = w * 4 + f, col = g * 16 + m;
        float s1 = 0.f, s2 = 0.f;
#pragma unroll
        for (int j = 0; j < 4; j++) {
            float v = acc[f][j];
            h1[(size_t)(row0 + q * 4 + j) * D_H + col] = v;
            s1 += v; s2 = fmaf(v, v, s2);
        }
        s1 += __shfl_xor(s1, 16, 64); s1 += __shfl_xor(s1, 32, 64);
        s2 += __shfl_xor(s2, 16, 64); s2 += __shfl_xor(s2, 32, 64);
        if (lane < 16) {
            partial[(size_t)blockIdx.x * 512 + col] = s1;
            partial[(size_t)blockIdx.x * 512 + 256 + col] = s2;
        }
    }
}

// ================================================================ BN finalize
__global__ __launch_bounds__(256) void bn_finalize_kernel(const float* __restrict__ partial,
                                                          const float* __restrict__ gamma,
                                                          const float* __restrict__ beta,
                                                          float* __restrict__ scale,
                                                          float* __restrict__ shift) {
    int s = blockIdx.x;
    int tid = threadIdx.x;
    float sum = 0.f, sq = 0.f;
    for (int b = tid; b < NB; b += 256) {
        sum += partial[(size_t)b * 512 + s];
        sq  += partial[(size_t)b * 512 + 256 + s];
    }
    __shared__ float rs[256], rq[256];
    rs[tid] = sum; rq[tid] = sq;
    __syncthreads();
    for (int off = 128; off > 0; off >>= 1) {
        if (tid < off) { rs[tid] += rs[tid + off]; rq[tid] += rq[tid + off]; }
        __syncthreads();
    }
    if (tid == 0) {
        float inv  = 1.0f / (float)N_NODES;
        float mean = rs[0] * inv;
        float var  = rq[0] * inv - mean * mean;
        float sc   = gamma[s] * rsqrtf(var + 1e-5f);
        scale[s] = sc;
        shift[s] = fmaf(-mean, sc, beta[s]);
    }
}

// ================================================================ GEMM2 (MFMA): out = relu(BN1(h1)) @ W2 + BN2 stats
__global__ __launch_bounds__(256) void gemm2_kernel(const float* __restrict__ h1,
                                                    const ushort* __restrict__ Wp,
                                                    const float* __restrict__ scale1,
                                                    const float* __restrict__ shift1,
                                                    float* __restrict__ out,
                                                    float* __restrict__ partial) {
    __shared__ ushort A[MT * D_H];    // 16x256 bf16, swizzled (stride 512 B)
    int tid = threadIdx.x, lane = tid & 63, w = tid >> 6;
    int row0 = blockIdx.x * MT;
    {
        int r = tid >> 4, c0 = (tid & 15) << 4;    // fp32 col
        const float* src = h1 + (size_t)(row0 + r) * D_H + c0;
        s16x8 lo, hi;
#pragma unroll
        for (int i = 0; i < 2; i++) {
            float4 v  = *(const float4*)(src + i * 4);
            float4 sc = *(const float4*)(scale1 + c0 + i * 4);
            float4 sh = *(const float4*)(shift1 + c0 + i * 4);
            lo[i*4+0] = (short)f2bf(fmaxf(fmaf(v.x, sc.x, sh.x), 0.f));
            lo[i*4+1] = (short)f2bf(fmaxf(fmaf(v.y, sc.y, sh.y), 0.f));
            lo[i*4+2] = (short)f2bf(fmaxf(fmaf(v.z, sc.z, sh.z), 0.f));
            lo[i*4+3] = (short)f2bf(fmaxf(fmaf(v.w, sc.w, sh.w), 0.f));
        }
#pragma unroll
        for (int i = 0; i < 2; i++) {
            float4 v  = *(const float4*)(src + 8 + i * 4);
            float4 sc = *(const float4*)(scale1 + c0 + 8 + i * 4);
            float4 sh = *(const float4*)(shift1 + c0 + 8 + i * 4);
            hi[i*4+0] = (short)f2bf(fmaxf(fmaf(v.x, sc.x, sh.x), 0.f));
            hi[i*4+1] = (short)f2bf(fmaxf(fmaf(v.y, sc.y, sh.y), 0.f));
            hi[i*4+2] = (short)f2bf(fmaxf(fmaf(v.z, sc.z, sh.z), 0.f));
            hi[i*4+3] = (short)f2bf(fmaxf(fmaf(v.w, sc.w, sh.w), 0.f));
        }
        int swr = (r & 7) << 4, base = r * 512, cb = c0 * 2;
        *(s16x8*)((char*)A + base + ( cb        ^ swr)) = lo;
        *(s16x8*)((char*)A + base + ((cb + 16)  ^ swr)) = hi;
    }
    __syncthreads();
    int m = lane & 15, q = lane >> 4;
    int sw = (m & 7) << 4;
    f32x4 acc[4] = {};
    const s16x8* B = (const s16x8*)Wp;
#pragma unroll
    for (int s = 0; s < 8; s++) {
        s16x8 a = *(const s16x8*)((char*)A + m * 512 + ((s * 64 + q * 16) ^ sw));
#pragma unroll
        for (int f = 0; f < 4; f++) {
            int g = w * 4 + f;
            s16x8 b = B[(s * 16 + g) * 64 + lane];
            acc[f] = __builtin_amdgcn_mfma_f32_16x16x32_bf16(a, b, acc[f], 0, 0, 0);
        }
    }
#pragma unroll
    for (int f = 0; f < 4; f++) {
        int g = w * 4 + f, col = g * 16 + m;
        float s1 = 0.f, s2 = 0.f;
#pragma unroll
        for (int j = 0; j < 4; j++) {
            float v = acc[f][j];
            out[(size_t)(row0 + q * 4 + j) * D_H + col] = v;
            s1 += v; s2 = fmaf(v, v, s2);
        }
        s1 += __shfl_xor(s1, 16, 64); s1 += __shfl_xor(s1, 32, 64);
        s2 += __shfl_xor(s2, 16, 64); s2 += __shfl_xor(s2, 32, 64);
        if (lane < 16) {
            partial[(size_t)blockIdx.x * 512 + col] = s1;
            partial[(size_t)blockIdx.x * 512 + 256 + col] = s2;
        }
    }
}

// ================================================================ final: out = relu(BN2(out)) in place
__global__ __launch_bounds__(256) void bn2_apply_kernel(float* __restrict__ out,
                                                        const float* __restrict__ scale,
                                                        const float* __restrict__ shift,
                                                        int total4) {
    int i = blockIdx.x * 256 + threadIdx.x;
    if (i >= total4) return;
    float4 v = ((float4*)out)[i];
    int c = (i & 63) << 2;
    float4 sc = *(const float4*)(scale + c);
    float4 sh = *(const float4*)(shift + c);
    v.x = fmaxf(fmaf(v.x, sc.x, sh.x), 0.f);
    v.y = fmaxf(fmaf(v.y, sc.y, sh.y), 0.f);
    v.z = fmaxf(fmaf(v.z, sc.z, sh.z), 0.f);
    v.w = fmaxf(fmaf(v.w, sc.w, sh.w), 0.f);
    ((float4*)out)[i] = v;
}

// ================================================================
extern "C" void kernel_launch(void* const* d_in, const int* in_sizes, int n_in,
                              void* d_out, int out_size, void* d_ws, size_t ws_size,
                              hipStream_t stream) {
    const float* x      = (const float*)d_in[0];
    const int*   ei     = (const int*)d_in[1];
    const float* eps    = (const float*)d_in[3];
    const float* W1     = (const float*)d_in[4];
    const float* gamma1 = (const float*)d_in[5];
    const float* beta1  = (const float*)d_in[6];
    const float* W2     = (const float*)d_in[7];
    const float* gamma2 = (const float*)d_in[8];
    const float* beta2  = (const float*)d_in[9];
    int E = in_sizes[1] / 2;

    char* ws = (char*)d_ws;
    ushort* hB     = (ushort*)(ws);                 // 12,800,000 B  bf16 h
    float*  h1     = (float*)(ws + 12800000);       // 51,200,000 B  (sort scratch pre-gemm1)
    float*  partial= (float*)(ws + 64000000);       //  6,400,000 B
    float*  stats  = (float*)(ws + 70400000);       //  4,096 B
    ushort* Wp1    = (ushort*)(ws + 70404096);      //  65,536 B
    ushort* Wp2    = (ushort*)(ws + 70469632);      // 131,072 B
    float* scale1 = stats, *shift1 = stats + 256, *scale2 = stats + 512, *shift2 = stats + 768;
    float* out = (float*)d_out;

    char* sb = (char*)h1;   // sort scratch overlaps h1 (dead until gemm1)
    int* count      = (int*)(sb);
    int* offset     = (int*)(sb + 200064);
    int* fill       = (int*)(sb + 400128);
    int* bsum       = (int*)(sb + 600192);
    int* sorted_src = (int*)(sb + 601216);

    hipMemsetAsync(count, 0, N_NODES * sizeof(int), stream);
    hipMemsetAsync(fill,  0, N_NODES * sizeof(int), stream);

    int eblk = (E + 255) / 256;
    pack_w_kernel<<<48, 256, 0, stream>>>(W1, W2, Wp1, Wp2);
    hist_kernel<<<eblk, 256, 0, stream>>>(ei, count, E);
    scan_blocks_kernel<<<SCAN_BLK, 256, 0, stream>>>(count, offset, bsum);
    scan_bsum_kernel<<<1, 256, 0, stream>>>(bsum);
    add_base_kernel<<<SCAN_BLK, 256, 0, stream>>>(offset, bsum);
    fill_kernel<<<eblk, 256, 0, stream>>>(ei, offset, fill, sorted_src, E);
    gather_kernel<<<(N_NODES + 7) / 8, 256, 0, stream>>>(x, eps, offset, count, sorted_src, hB);

    gemm1_kernel<<<NB, 256, 0, stream>>>(hB, Wp1, h1, partial);
    bn_finalize_kernel<<<D_H, 256, 0, stream>>>(partial, gamma1, beta1, scale1, shift1);
    gemm2_kernel<<<NB, 256, 0, stream>>>(h1, Wp2, scale1, shift1, out, partial);
    bn_finalize_kernel<<<D_H, 256, 0, stream>>>(partial, gamma2, beta2, scale2, shift2);
    bn2_apply_kernel<<<(N_NODES * D_H / 4 + 255) / 256, 256, 0, stream>>>(out, scale2, shift2, N_NODES * D_H / 4);
}

// Round 7
// 219.401 us; speedup vs baseline: 7.2388x; 1.0955x over previous
//
#include <hip/hip_runtime.h>

#define N_NODES 50000
#define D_IN    128
#define D_H     256
#define MT      16
#define NB      (N_NODES / MT)           // 3125 exact, no tail
#define SCAN_BLK ((N_NODES + 255) / 256) // 196

typedef short s16x8 __attribute__((ext_vector_type(8)));
typedef short s16x4 __attribute__((ext_vector_type(4)));
typedef float f32x4 __attribute__((ext_vector_type(4)));

__device__ inline ushort f2bf(float f) {           // RNE fp32->bf16
    uint u = __float_as_uint(f);
    return (ushort)((u + 0x7FFFu + ((u >> 16) & 1u)) >> 16);
}
__device__ inline float bf2f(ushort u) { return __uint_as_float(((uint)u) << 16); }

// ================================================================ x -> bf16
__global__ __launch_bounds__(256) void cvt_x_kernel(const float* __restrict__ x,
                                                    ushort* __restrict__ xB, int total8) {
    int i = blockIdx.x * 256 + threadIdx.x;
    if (i >= total8) return;
    float4 a = ((const float4*)x)[(size_t)i * 2];
    float4 b = ((const float4*)x)[(size_t)i * 2 + 1];
    s16x8 o;
    o[0] = (short)f2bf(a.x); o[1] = (short)f2bf(a.y);
    o[2] = (short)f2bf(a.z); o[3] = (short)f2bf(a.w);
    o[4] = (short)f2bf(b.x); o[5] = (short)f2bf(b.y);
    o[6] = (short)f2bf(b.z); o[7] = (short)f2bf(b.w);
    ((s16x8*)xB)[i] = o;
}

// ================================================================ aggregation (sort-based)
__global__ __launch_bounds__(256) void hist_kernel(const int* __restrict__ ei, int* __restrict__ count, int E) {
    int e = blockIdx.x * 256 + threadIdx.x;
    if (e >= E) return;
    atomicAdd(&count[ei[E + e]], 1);
}

__global__ __launch_bounds__(256) void scan_blocks_kernel(const int* __restrict__ count,
                                                          int* __restrict__ offset,
                                                          int* __restrict__ bsum) {
    __shared__ int sh[256];
    int tid = threadIdx.x;
    int i = blockIdx.x * 256 + tid;
    int v = (i < N_NODES) ? count[i] : 0;
    sh[tid] = v;
    __syncthreads();
    for (int off = 1; off < 256; off <<= 1) {
        int t = (tid >= off) ? sh[tid - off] : 0;
        __syncthreads();
        sh[tid] += t;
        __syncthreads();
    }
    if (i < N_NODES) offset[i] = sh[tid] - v;
    if (tid == 255) bsum[blockIdx.x] = sh[255];
}

__global__ __launch_bounds__(256) void scan_bsum_kernel(int* __restrict__ bsum) {
    __shared__ int sh[256];
    int tid = threadIdx.x;
    int v = (tid < SCAN_BLK) ? bsum[tid] : 0;
    sh[tid] = v;
    __syncthreads();
    for (int off = 1; off < 256; off <<= 1) {
        int t = (tid >= off) ? sh[tid - off] : 0;
        __syncthreads();
        sh[tid] += t;
        __syncthreads();
    }
    if (tid < SCAN_BLK) bsum[tid] = sh[tid] - v;
}

__global__ __launch_bounds__(256) void add_base_kernel(int* __restrict__ offset, const int* __restrict__ bsum) {
    int i = blockIdx.x * 256 + threadIdx.x;
    if (i < N_NODES) offset[i] += bsum[blockIdx.x];
}

__global__ __launch_bounds__(256) void fill_kernel(const int* __restrict__ ei,
                                                   const int* __restrict__ offset,
                                                   int* __restrict__ fill,
                                                   int* __restrict__ sorted_src, int E) {
    int e = blockIdx.x * 256 + threadIdx.x;
    if (e >= E) return;
    int src = ei[e];
    int dst = ei[E + e];
    int pos = offset[dst] + atomicAdd(&fill[dst], 1);
    sorted_src[pos] = src;
}

// gather-sum over bf16 x -> bf16 h
__global__ __launch_bounds__(256) void gather_kernel(const ushort* __restrict__ xB,
                                                     const float* __restrict__ eps,
                                                     const int* __restrict__ offset,
                                                     const int* __restrict__ count,
                                                     const int* __restrict__ sorted_src,
                                                     ushort* __restrict__ h) {
    int g = threadIdx.x >> 5, lane = threadIdx.x & 31;
    int d = blockIdx.x * 8 + g;
    if (d >= N_NODES) return;
    int c = lane << 2;
    float s = 1.0f + eps[0];
    s16x4 sv = *(const s16x4*)(xB + (size_t)d * D_IN + c);
    float a0 = bf2f((ushort)sv[0]) * s, a1 = bf2f((ushort)sv[1]) * s,
          a2 = bf2f((ushort)sv[2]) * s, a3 = bf2f((ushort)sv[3]) * s;
    int beg = offset[d], cnt = count[d];
    int j = 0;
    for (; j + 3 < cnt; j += 4) {
        int s0 = sorted_src[beg + j],     s1 = sorted_src[beg + j + 1];
        int s2 = sorted_src[beg + j + 2], s3 = sorted_src[beg + j + 3];
        s16x4 v0 = *(const s16x4*)(xB + (size_t)s0 * D_IN + c);
        s16x4 v1 = *(const s16x4*)(xB + (size_t)s1 * D_IN + c);
        s16x4 v2 = *(const s16x4*)(xB + (size_t)s2 * D_IN + c);
        s16x4 v3 = *(const s16x4*)(xB + (size_t)s3 * D_IN + c);
        a0 += bf2f((ushort)v0[0]) + bf2f((ushort)v1[0]) + bf2f((ushort)v2[0]) + bf2f((ushort)v3[0]);
        a1 += bf2f((ushort)v0[1]) + bf2f((ushort)v1[1]) + bf2f((ushort)v2[1]) + bf2f((ushort)v3[1]);
        a2 += bf2f((ushort)v0[2]) + bf2f((ushort)v1[2]) + bf2f((ushort)v2[2]) + bf2f((ushort)v3[2]);
        a3 += bf2f((ushort)v0[3]) + bf2f((ushort)v1[3]) + bf2f((ushort)v2[3]) + bf2f((ushort)v3[3]);
    }
    for (; j < cnt; j++) {
        int s0 = sorted_src[beg + j];
        s16x4 v0 = *(const s16x4*)(xB + (size_t)s0 * D_IN + c);
        a0 += bf2f((ushort)v0[0]); a1 += bf2f((ushort)v0[1]);
        a2 += bf2f((ushort)v0[2]); a3 += bf2f((ushort)v0[3]);
    }
    s16x4 o;
    o[0] = (short)f2bf(a0); o[1] = (short)f2bf(a1);
    o[2] = (short)f2bf(a2); o[3] = (short)f2bf(a3);
    *(s16x4*)(h + (size_t)d * D_IN + c) = o;
}

// ================================================================ W pack: fragment-order bf16
__global__ __launch_bounds__(256) void pack_w_kernel(const float* __restrict__ W1,
                                                     const float* __restrict__ W2,
                                                     ushort* __restrict__ Wp1,
                                                     ushort* __restrict__ Wp2) {
    int t = blockIdx.x * 256 + threadIdx.x;
    const float* W; ushort* Wp; int u;
    if (t < 4096)       { W = W1; Wp = Wp1; u = t; }
    else if (t < 12288) { W = W2; Wp = Wp2; u = t - 4096; }
    else return;
    int l = u & 63, gs = u >> 6;
    int g = gs & 15, s = gs >> 4;
    int col = g * 16 + (l & 15), q = l >> 4;
    s16x8 o;
#pragma unroll
    for (int j = 0; j < 8; j++) {
        int k = s * 32 + q * 8 + j;
        o[j] = (short)f2bf(W[(size_t)k * D_H + col]);
    }
    *(s16x8*)(Wp + (size_t)u * 8) = o;
}

// ================================================================ GEMM1 (MFMA): h1B = h @ W1 (bf16 out) + BN1 stats
__global__ __launch_bounds__(256) void gemm1_kernel(const ushort* __restrict__ hB,
                                                    const ushort* __restrict__ Wp,
                                                    ushort* __restrict__ h1B,
                                                    float* __restrict__ partial) {
    __shared__ ushort A[MT * D_IN];   // 16x128 bf16, XOR-swizzled rows (stride 256 B)
    int tid = threadIdx.x, lane = tid & 63, w = tid >> 6;
    int row0 = blockIdx.x * MT;
    {
        int r = tid >> 4, cb = (tid & 15) << 4;
        s16x8 v = *(const s16x8*)(hB + (size_t)(row0 + r) * D_IN + (cb >> 1));
        *(s16x8*)((char*)A + r * 256 + (cb ^ ((r & 7) << 4))) = v;
    }
    __syncthreads();
    int m = lane & 15, q = lane >> 4;
    int sw = (m & 7) << 4;
    f32x4 acc[4] = {};
    const s16x8* B = (const s16x8*)Wp;
#pragma unroll
    for (int s = 0; s < 4; s++) {
        s16x8 a = *(const s16x8*)((char*)A + m * 256 + ((s * 64 + q * 16) ^ sw));
#pragma unroll
        for (int f = 0; f < 4; f++) {
            int g = w * 4 + f;
            s16x8 b = B[(s * 16 + g) * 64 + lane];
            acc[f] = __builtin_amdgcn_mfma_f32_16x16x32_bf16(a, b, acc[f], 0, 0, 0);
        }
    }
#pragma unroll
    for (int f = 0; f < 4; f++) {
        int g = w * 4 + f, col = g * 16 + m;
        float s1 = 0.f, s2 = 0.f;
#pragma unroll
        for (int j = 0; j < 4; j++) {
            float v = acc[f][j];
            h1B[(size_t)(row0 + q * 4 + j) * D_H + col] = f2bf(v);
            s1 += v; s2 = fmaf(v, v, s2);
        }
        s1 += __shfl_xor(s1, 16, 64); s1 += __shfl_xor(s1, 32, 64);
        s2 += __shfl_xor(s2, 16, 64); s2 += __shfl_xor(s2, 32, 64);
        if (lane < 16) {
            partial[(size_t)blockIdx.x * 512 + col] = s1;
            partial[(size_t)blockIdx.x * 512 + 256 + col] = s2;
        }
    }
}

// ================================================================ BN finalize
__global__ __launch_bounds__(256) void bn_finalize_kernel(const float* __restrict__ partial,
                                                          const float* __restrict__ gamma,
                                                          const float* __restrict__ beta,
                                                          float* __restrict__ scale,
                                                          float* __restrict__ shift) {
    int s = blockIdx.x;
    int tid = threadIdx.x;
    float sum = 0.f, sq = 0.f;
    for (int b = tid; b < NB; b += 256) {
        sum += partial[(size_t)b * 512 + s];
        sq  += partial[(size_t)b * 512 + 256 + s];
    }
    __shared__ float rs[256], rq[256];
    rs[tid] = sum; rq[tid] = sq;
    __syncthreads();
    for (int off = 128; off > 0; off >>= 1) {
        if (tid < off) { rs[tid] += rs[tid + off]; rq[tid] += rq[tid + off]; }
        __syncthreads();
    }
    if (tid == 0) {
        float inv  = 1.0f / (float)N_NODES;
        float mean = rs[0] * inv;
        float var  = rq[0] * inv - mean * mean;
        float sc   = gamma[s] * rsqrtf(var + 1e-5f);
        scale[s] = sc;
        shift[s] = fmaf(-mean, sc, beta[s]);
    }
}

// ================================================================ GEMM2 (MFMA): h2B = relu(BN1(h1B)) @ W2 (bf16 out) + BN2 stats
__global__ __launch_bounds__(256) void gemm2_kernel(const ushort* __restrict__ h1B,
                                                    const ushort* __restrict__ Wp,
                                                    const float* __restrict__ scale1,
                                                    const float* __restrict__ shift1,
                                                    ushort* __restrict__ h2B,
                                                    float* __restrict__ partial) {
    __shared__ ushort A[MT * D_H];    // 16x256 bf16, swizzled (stride 512 B)
    int tid = threadIdx.x, lane = tid & 63, w = tid >> 6;
    int row0 = blockIdx.x * MT;
    {
        int r = tid >> 4, c0 = (tid & 15) << 4;
        const ushort* srcp = h1B + (size_t)(row0 + r) * D_H + c0;
        s16x8 in0 = *(const s16x8*)(srcp);
        s16x8 in1 = *(const s16x8*)(srcp + 8);
        s16x8 lo, hi;
#pragma unroll
        for (int i = 0; i < 8; i++) {
            float v = fmaxf(fmaf(bf2f((ushort)in0[i]), scale1[c0 + i], shift1[c0 + i]), 0.f);
            lo[i] = (short)f2bf(v);
        }
#pragma unroll
        for (int i = 0; i < 8; i++) {
            float v = fmaxf(fmaf(bf2f((ushort)in1[i]), scale1[c0 + 8 + i], shift1[c0 + 8 + i]), 0.f);
            hi[i] = (short)f2bf(v);
        }
        int swr = (r & 7) << 4, base = r * 512, cb = c0 * 2;
        *(s16x8*)((char*)A + base + ( cb        ^ swr)) = lo;
        *(s16x8*)((char*)A + base + ((cb + 16)  ^ swr)) = hi;
    }
    __syncthreads();
    int m = lane & 15, q = lane >> 4;
    int sw = (m & 7) << 4;
    f32x4 acc[4] = {};
    const s16x8* B = (const s16x8*)Wp;
#pragma unroll
    for (int s = 0; s < 8; s++) {
        s16x8 a = *(const s16x8*)((char*)A + m * 512 + ((s * 64 + q * 16) ^ sw));
#pragma unroll
        for (int f = 0; f < 4; f++) {
            int g = w * 4 + f;
            s16x8 b = B[(s * 16 + g) * 64 + lane];
            acc[f] = __builtin_amdgcn_mfma_f32_16x16x32_bf16(a, b, acc[f], 0, 0, 0);
        }
    }
#pragma unroll
    for (int f = 0; f < 4; f++) {
        int g = w * 4 + f, col = g * 16 + m;
        float s1 = 0.f, s2 = 0.f;
#pragma unroll
        for (int j = 0; j < 4; j++) {
            float v = acc[f][j];
            h2B[(size_t)(row0 + q * 4 + j) * D_H + col] = f2bf(v);
            s1 += v; s2 = fmaf(v, v, s2);
        }
        s1 += __shfl_xor(s1, 16, 64); s1 += __shfl_xor(s1, 32, 64);
        s2 += __shfl_xor(s2, 16, 64); s2 += __shfl_xor(s2, 32, 64);
        if (lane < 16) {
            partial[(size_t)blockIdx.x * 512 + col] = s1;
            partial[(size_t)blockIdx.x * 512 + 256 + col] = s2;
        }
    }
}

// ================================================================ final: out = relu(BN2(h2B)) -> fp32
__global__ __launch_bounds__(256) void bn2_apply_kernel(const ushort* __restrict__ h2B,
                                                        const float* __restrict__ scale,
                                                        const float* __restrict__ shift,
                                                        float* __restrict__ out, int total8) {
    int i = blockIdx.x * 256 + threadIdx.x;
    if (i >= total8) return;
    s16x8 v = ((const s16x8*)h2B)[i];
    int c = (i & 31) << 3;
    float4 sc0 = *(const float4*)(scale + c), sc1 = *(const float4*)(scale + c + 4);
    float4 sh0 = *(const float4*)(shift + c), sh1 = *(const float4*)(shift + c + 4);
    float4 o0, o1;
    o0.x = fmaxf(fmaf(bf2f((ushort)v[0]), sc0.x, sh0.x), 0.f);
    o0.y = fmaxf(fmaf(bf2f((ushort)v[1]), sc0.y, sh0.y), 0.f);
    o0.z = fmaxf(fmaf(bf2f((ushort)v[2]), sc0.z, sh0.z), 0.f);
    o0.w = fmaxf(fmaf(bf2f((ushort)v[3]), sc0.w, sh0.w), 0.f);
    o1.x = fmaxf(fmaf(bf2f((ushort)v[4]), sc1.x, sh1.x), 0.f);
    o1.y = fmaxf(fmaf(bf2f((ushort)v[5]), sc1.y, sh1.y), 0.f);
    o1.z = fmaxf(fmaf(bf2f((ushort)v[6]), sc1.z, sh1.z), 0.f);
    o1.w = fmaxf(fmaf(bf2f((ushort)v[7]), sc1.w, sh1.w), 0.f);
    ((float4*)out)[(size_t)i * 2]     = o0;
    ((float4*)out)[(size_t)i * 2 + 1] = o1;
}

// ================================================================
extern "C" void kernel_launch(void* const* d_in, const int* in_sizes, int n_in,
                              void* d_out, int out_size, void* d_ws, size_t ws_size,
                              hipStream_t stream) {
    const float* x      = (const float*)d_in[0];
    const int*   ei     = (const int*)d_in[1];
    const float* eps    = (const float*)d_in[3];
    const float* W1     = (const float*)d_in[4];
    const float* gamma1 = (const float*)d_in[5];
    const float* beta1  = (const float*)d_in[6];
    const float* W2     = (const float*)d_in[7];
    const float* gamma2 = (const float*)d_in[8];
    const float* beta2  = (const float*)d_in[9];
    int E = in_sizes[1] / 2;

    char* ws = (char*)d_ws;
    ushort* xB     = (ushort*)(ws);                 // 12,800,000 B (dead after gather)
    float*  partial= (float*)(ws);                  // 6,400,000 B  (overlaps xB; live from gemm1)
    ushort* hB     = (ushort*)(ws + 12800000);      // 12,800,000 B
    ushort* h1B    = (ushort*)(ws + 25600000);      // 25,600,000 B
    ushort* h2B    = (ushort*)(ws + 51200000);      // 25,600,000 B (overlaps sort scratch)
    float*  stats  = (float*)(ws + 76800000);       // 4,096 B
    ushort* Wp1    = (ushort*)(ws + 76804096);      // 65,536 B
    ushort* Wp2    = (ushort*)(ws + 76869632);      // 131,072 B -> end 77,000,704
    float* scale1 = stats, *shift1 = stats + 256, *scale2 = stats + 512, *shift2 = stats + 768;
    float* out = (float*)d_out;

    char* sb = (char*)h2B;   // sort scratch (dead before gemm2 writes h2B)
    int* count      = (int*)(sb);
    int* offset     = (int*)(sb + 200064);
    int* fill       = (int*)(sb + 400128);
    int* bsum       = (int*)(sb + 600192);
    int* sorted_src = (int*)(sb + 601216);

    hipMemsetAsync(count, 0, N_NODES * sizeof(int), stream);
    hipMemsetAsync(fill,  0, N_NODES * sizeof(int), stream);

    int eblk = (E + 255) / 256;
    cvt_x_kernel<<<(800000 + 255) / 256, 256, 0, stream>>>(x, xB, 800000);
    pack_w_kernel<<<48, 256, 0, stream>>>(W1, W2, Wp1, Wp2);
    hist_kernel<<<eblk, 256, 0, stream>>>(ei, count, E);
    scan_blocks_kernel<<<SCAN_BLK, 256, 0, stream>>>(count, offset, bsum);
    scan_bsum_kernel<<<1, 256, 0, stream>>>(bsum);
    add_base_kernel<<<SCAN_BLK, 256, 0, stream>>>(offset, bsum);
    fill_kernel<<<eblk, 256, 0, stream>>>(ei, offset, fill, sorted_src, E);
    gather_kernel<<<(N_NODES + 7) / 8, 256, 0, stream>>>(xB, eps, offset, count, sorted_src, hB);

    gemm1_kernel<<<NB, 256, 0, stream>>>(hB, Wp1, h1B, partial);
    bn_finalize_kernel<<<D_H, 256, 0, stream>>>(partial, gamma1, beta1, scale1, shift1);
    gemm2_kernel<<<NB, 256, 0, stream>>>(h1B, Wp2, scale1, shift1, h2B, partial);
    bn_finalize_kernel<<<D_H, 256, 0, stream>>>(partial, gamma2, beta2, scale2, shift2);
    bn2_apply_kernel<<<(1600000 + 255) / 256, 256, 0, stream>>>(h2B, scale2, shift2, out, 1600000);
}

// Round 8
// 161.073 us; speedup vs baseline: 9.8601x; 1.3621x over previous
//
#include <hip/hip_runtime.h>

#define N_NODES 50000
#define D_IN    128
#define D_H     256
#define MT      16
#define NB      (N_NODES / MT)           // 3125 exact, no tail

#define NBKT    391                      // ceil(50000/128) dst-buckets of 128 nodes
#define BKT_CAP 3072                     // mean 2046 + 23 sigma for uniform edges
#define EPB     8192                     // edges per bucket_kernel block

typedef short s16x8 __attribute__((ext_vector_type(8)));
typedef short s16x4 __attribute__((ext_vector_type(4)));
typedef float f32x4 __attribute__((ext_vector_type(4)));

__device__ inline ushort f2bf(float f) {           // RNE fp32->bf16
    uint u = __float_as_uint(f);
    return (ushort)((u + 0x7FFFu + ((u >> 16) & 1u)) >> 16);
}
__device__ inline float bf2f(ushort u) { return __uint_as_float(((uint)u) << 16); }

// ================================================================ x -> bf16
__global__ __launch_bounds__(256) void cvt_x_kernel(const float* __restrict__ x,
                                                    ushort* __restrict__ xB, int total8) {
    int i = blockIdx.x * 256 + threadIdx.x;
    if (i >= total8) return;
    float4 a = ((const float4*)x)[(size_t)i * 2];
    float4 b = ((const float4*)x)[(size_t)i * 2 + 1];
    s16x8 o;
    o[0] = (short)f2bf(a.x); o[1] = (short)f2bf(a.y);
    o[2] = (short)f2bf(a.z); o[3] = (short)f2bf(a.w);
    o[4] = (short)f2bf(b.x); o[5] = (short)f2bf(b.y);
    o[6] = (short)f2bf(b.z); o[7] = (short)f2bf(b.w);
    ((s16x8*)xB)[i] = o;
}

// ================================================================ pass A: bucket edges by dst>>7
// rec = (dst&127)<<16 | src   (src < 50000 < 2^16)
__global__ __launch_bounds__(256) void bucket_kernel(const int* __restrict__ ei,
                                                     int* __restrict__ bucket_fill,
                                                     uint* __restrict__ bucket_buf, int E) {
    __shared__ int cnt[NBKT], gbase[NBKT], fill2[NBKT];
    int tid = threadIdx.x;
    int e0 = blockIdx.x * EPB;
    for (int i = tid; i < NBKT; i += 256) { cnt[i] = 0; fill2[i] = 0; }
    __syncthreads();
    int dstv[32];
#pragma unroll
    for (int j = 0; j < 32; j++) {
        int e = e0 + j * 256 + tid;
        dstv[j] = (e < E) ? ei[E + e] : -1;
        if (dstv[j] >= 0) atomicAdd(&cnt[dstv[j] >> 7], 1);
    }
    __syncthreads();
    for (int i = tid; i < NBKT; i += 256) {
        int c = cnt[i];
        gbase[i] = c ? atomicAdd(&bucket_fill[i], c) : 0;
    }
    __syncthreads();
#pragma unroll
    for (int j = 0; j < 32; j++) {
        int e = e0 + j * 256 + tid;
        if (dstv[j] >= 0) {
            int src = ei[e];
            int b = dstv[j] >> 7;
            int p = atomicAdd(&fill2[b], 1);
            bucket_buf[(size_t)b * BKT_CAP + gbase[b] + p] =
                ((uint)(dstv[j] & 127) << 16) | (uint)src;
        }
    }
}

// ================================================================ pass B: per-bucket LDS counting sort + gather
// h[d] = (1+eps)*x[d] + sum_{src} x[src], bf16 in/out, fp32 accum
__global__ __launch_bounds__(512) void gather_bucket_kernel(const ushort* __restrict__ xB,
                                                            const float* __restrict__ eps,
                                                            const int* __restrict__ bucket_fill,
                                                            const uint* __restrict__ bucket_buf,
                                                            ushort* __restrict__ h) {
    __shared__ uint   raw[BKT_CAP];     // 12 KB
    __shared__ ushort srt[BKT_CAP];     //  6 KB
    __shared__ int cnt[128], off[128], f2[128];
    int b = blockIdx.x, tid = threadIdx.x;
    int n = bucket_fill[b];
    if (n > BKT_CAP) n = BKT_CAP;       // safety clamp
    for (int i = tid; i < n; i += 512) raw[i] = bucket_buf[(size_t)b * BKT_CAP + i];
    if (tid < 128) { cnt[tid] = 0; f2[tid] = 0; }
    __syncthreads();
    for (int i = tid; i < n; i += 512) atomicAdd(&cnt[raw[i] >> 16], 1);
    __syncthreads();
    if (tid < 128) off[tid] = cnt[tid];
    __syncthreads();
    for (int s2 = 1; s2 < 128; s2 <<= 1) {       // inclusive scan
        int t = (tid < 128 && tid >= s2) ? off[tid - s2] : 0;
        __syncthreads();
        if (tid < 128) off[tid] += t;
        __syncthreads();
    }
    for (int i = tid; i < n; i += 512) {
        uint r = raw[i];
        int d = r >> 16;
        int p = atomicAdd(&f2[d], 1);
        srt[(off[d] - cnt[d]) + p] = (ushort)(r & 0xFFFFu);
    }
    __syncthreads();

    int grp = tid >> 5, lane = tid & 31;
    int c = lane << 2;
    float s = 1.0f + eps[0];
    for (int dl = grp; dl < 128; dl += 16) {
        int d = b * 128 + dl;
        if (d >= N_NODES) break;
        int st = off[dl] - cnt[dl], cn = cnt[dl];
        s16x4 sv = *(const s16x4*)(xB + (size_t)d * D_IN + c);
        float a0 = bf2f((ushort)sv[0]) * s, a1 = bf2f((ushort)sv[1]) * s,
              a2 = bf2f((ushort)sv[2]) * s, a3 = bf2f((ushort)sv[3]) * s;
        int j = 0;
        for (; j + 3 < cn; j += 4) {
            int s0 = srt[st + j],     s1 = srt[st + j + 1];
            int s2 = srt[st + j + 2], s3 = srt[st + j + 3];
            s16x4 v0 = *(const s16x4*)(xB + (size_t)s0 * D_IN + c);
            s16x4 v1 = *(const s16x4*)(xB + (size_t)s1 * D_IN + c);
            s16x4 v2 = *(const s16x4*)(xB + (size_t)s2 * D_IN + c);
            s16x4 v3 = *(const s16x4*)(xB + (size_t)s3 * D_IN + c);
            a0 += bf2f((ushort)v0[0]) + bf2f((ushort)v1[0]) + bf2f((ushort)v2[0]) + bf2f((ushort)v3[0]);
            a1 += bf2f((ushort)v0[1]) + bf2f((ushort)v1[1]) + bf2f((ushort)v2[1]) + bf2f((ushort)v3[1]);
            a2 += bf2f((ushort)v0[2]) + bf2f((ushort)v1[2]) + bf2f((ushort)v2[2]) + bf2f((ushort)v3[2]);
            a3 += bf2f((ushort)v0[3]) + bf2f((ushort)v1[3]) + bf2f((ushort)v2[3]) + bf2f((ushort)v3[3]);
        }
        for (; j < cn; j++) {
            int s0 = srt[st + j];
            s16x4 v0 = *(const s16x4*)(xB + (size_t)s0 * D_IN + c);
            a0 += bf2f((ushort)v0[0]); a1 += bf2f((ushort)v0[1]);
            a2 += bf2f((ushort)v0[2]); a3 += bf2f((ushort)v0[3]);
        }
        s16x4 o;
        o[0] = (short)f2bf(a0); o[1] = (short)f2bf(a1);
        o[2] = (short)f2bf(a2); o[3] = (short)f2bf(a3);
        *(s16x4*)(h + (size_t)d * D_IN + c) = o;
    }
}

// ================================================================ W pack: fragment-order bf16
__global__ __launch_bounds__(256) void pack_w_kernel(const float* __restrict__ W1,
                                                     const float* __restrict__ W2,
                                                     ushort* __restrict__ Wp1,
                                                     ushort* __restrict__ Wp2) {
    int t = blockIdx.x * 256 + threadIdx.x;
    const float* W; ushort* Wp; int u;
    if (t < 4096)       { W = W1; Wp = Wp1; u = t; }
    else if (t < 12288) { W = W2; Wp = Wp2; u = t - 4096; }
    else return;
    int l = u & 63, gs = u >> 6;
    int g = gs & 15, s = gs >> 4;
    int col = g * 16 + (l & 15), q = l >> 4;
    s16x8 o;
#pragma unroll
    for (int j = 0; j < 8; j++) {
        int k = s * 32 + q * 8 + j;
        o[j] = (short)f2bf(W[(size_t)k * D_H + col]);
    }
    *(s16x8*)(Wp + (size_t)u * 8) = o;
}

// ================================================================ GEMM1 (MFMA): h1B = h @ W1 (bf16 out) + BN1 stats
__global__ __launch_bounds__(256) void gemm1_kernel(const ushort* __restrict__ hB,
                                                    const ushort* __restrict__ Wp,
                                                    ushort* __restrict__ h1B,
                                                    float* __restrict__ partial) {
    __shared__ ushort A[MT * D_IN];   // 16x128 bf16, XOR-swizzled rows (stride 256 B)
    int tid = threadIdx.x, lane = tid & 63, w = tid >> 6;
    int row0 = blockIdx.x * MT;
    {
        int r = tid >> 4, cb = (tid & 15) << 4;
        s16x8 v = *(const s16x8*)(hB + (size_t)(row0 + r) * D_IN + (cb >> 1));
        *(s16x8*)((char*)A + r * 256 + (cb ^ ((r & 7) << 4))) = v;
    }
    __syncthreads();
    int m = lane & 15, q = lane >> 4;
    int sw = (m & 7) << 4;
    f32x4 acc[4] = {};
    const s16x8* B = (const s16x8*)Wp;
#pragma unroll
    for (int s = 0; s < 4; s++) {
        s16x8 a = *(const s16x8*)((char*)A + m * 256 + ((s * 64 + q * 16) ^ sw));
#pragma unroll
        for (int f = 0; f < 4; f++) {
            int g = w * 4 + f;
            s16x8 b = B[(s * 16 + g) * 64 + lane];
            acc[f] = __builtin_amdgcn_mfma_f32_16x16x32_bf16(a, b, acc[f], 0, 0, 0);
        }
    }
#pragma unroll
    for (int f = 0; f < 4; f++) {
        int g = w * 4 + f, col = g * 16 + m;
        float s1 = 0.f, s2 = 0.f;
#pragma unroll
        for (int j = 0; j < 4; j++) {
            float v = acc[f][j];
            h1B[(size_t)(row0 + q * 4 + j) * D_H + col] = f2bf(v);
            s1 += v; s2 = fmaf(v, v, s2);
        }
        s1 += __shfl_xor(s1, 16, 64); s1 += __shfl_xor(s1, 32, 64);
        s2 += __shfl_xor(s2, 16, 64); s2 += __shfl_xor(s2, 32, 64);
        if (lane < 16) {
            partial[(size_t)blockIdx.x * 512 + col] = s1;
            partial[(size_t)blockIdx.x * 512 + 256 + col] = s2;
        }
    }
}

// ================================================================ BN finalize
__global__ __launch_bounds__(256) void bn_finalize_kernel(const float* __restrict__ partial,
                                                          const float* __restrict__ gamma,
                                                          const float* __restrict__ beta,
                                                          float* __restrict__ scale,
                                                          float* __restrict__ shift) {
    int s = blockIdx.x;
    int tid = threadIdx.x;
    float sum = 0.f, sq = 0.f;
    for (int b = tid; b < NB; b += 256) {
        sum += partial[(size_t)b * 512 + s];
        sq  += partial[(size_t)b * 512 + 256 + s];
    }
    __shared__ float rs[256], rq[256];
    rs[tid] = sum; rq[tid] = sq;
    __syncthreads();
    for (int off = 128; off > 0; off >>= 1) {
        if (tid < off) { rs[tid] += rs[tid + off]; rq[tid] += rq[tid + off]; }
        __syncthreads();
    }
    if (tid == 0) {
        float inv  = 1.0f / (float)N_NODES;
        float mean = rs[0] * inv;
        float var  = rq[0] * inv - mean * mean;
        float sc   = gamma[s] * rsqrtf(var + 1e-5f);
        scale[s] = sc;
        shift[s] = fmaf(-mean, sc, beta[s]);
    }
}

// ================================================================ GEMM2 (MFMA): h2B = relu(BN1(h1B)) @ W2 (bf16 out) + BN2 stats
__global__ __launch_bounds__(256) void gemm2_kernel(const ushort* __restrict__ h1B,
                                                    const ushort* __restrict__ Wp,
                                                    const float* __restrict__ scale1,
                                                    const float* __restrict__ shift1,
                                                    ushort* __restrict__ h2B,
                                                    float* __restrict__ partial) {
    __shared__ ushort A[MT * D_H];    // 16x256 bf16, swizzled (stride 512 B)
    int tid = threadIdx.x, lane = tid & 63, w = tid >> 6;
    int row0 = blockIdx.x * MT;
    {
        int r = tid >> 4, c0 = (tid & 15) << 4;
        const ushort* srcp = h1B + (size_t)(row0 + r) * D_H + c0;
        s16x8 in0 = *(const s16x8*)(srcp);
        s16x8 in1 = *(const s16x8*)(srcp + 8);
        s16x8 lo, hi;
#pragma unroll
        for (int i = 0; i < 8; i++) {
            float v = fmaxf(fmaf(bf2f((ushort)in0[i]), scale1[c0 + i], shift1[c0 + i]), 0.f);
            lo[i] = (short)f2bf(v);
        }
#pragma unroll
        for (int i = 0; i < 8; i++) {
            float v = fmaxf(fmaf(bf2f((ushort)in1[i]), scale1[c0 + 8 + i], shift1[c0 + 8 + i]), 0.f);
            hi[i] = (short)f2bf(v);
        }
        int swr = (r & 7) << 4, base = r * 512, cb = c0 * 2;
        *(s16x8*)((char*)A + base + ( cb        ^ swr)) = lo;
        *(s16x8*)((char*)A + base + ((cb + 16)  ^ swr)) = hi;
    }
    __syncthreads();
    int m = lane & 15, q = lane >> 4;
    int sw = (m & 7) << 4;
    f32x4 acc[4] = {};
    const s16x8* B = (const s16x8*)Wp;
#pragma unroll
    for (int s = 0; s < 8; s++) {
        s16x8 a = *(const s16x8*)((char*)A + m * 512 + ((s * 64 + q * 16) ^ sw));
#pragma unroll
        for (int f = 0; f < 4; f++) {
            int g = w * 4 + f;
            s16x8 b = B[(s * 16 + g) * 64 + lane];
            acc[f] = __builtin_amdgcn_mfma_f32_16x16x32_bf16(a, b, acc[f], 0, 0, 0);
        }
    }
#pragma unroll
    for (int f = 0; f < 4; f++) {
        int g = w * 4 + f, col = g * 16 + m;
        float s1 = 0.f, s2 = 0.f;
#pragma unroll
        for (int j = 0; j < 4; j++) {
            float v = acc[f][j];
            h2B[(size_t)(row0 + q * 4 + j) * D_H + col] = f2bf(v);
            s1 += v; s2 = fmaf(v, v, s2);
        }
        s1 += __shfl_xor(s1, 16, 64); s1 += __shfl_xor(s1, 32, 64);
        s2 += __shfl_xor(s2, 16, 64); s2 += __shfl_xor(s2, 32, 64);
        if (lane < 16) {
            partial[(size_t)blockIdx.x * 512 + col] = s1;
            partial[(size_t)blockIdx.x * 512 + 256 + col] = s2;
        }
    }
}

// ================================================================ final: out = relu(BN2(h2B)) -> fp32
__global__ __launch_bounds__(256) void bn2_apply_kernel(const ushort* __restrict__ h2B,
                                                        const float* __restrict__ scale,
                                                        const float* __restrict__ shift,
                                                        float* __restrict__ out, int total8) {
    int i = blockIdx.x * 256 + threadIdx.x;
    if (i >= total8) return;
    s16x8 v = ((const s16x8*)h2B)[i];
    int c = (i & 31) << 3;
    float4 sc0 = *(const float4*)(scale + c), sc1 = *(const float4*)(scale + c + 4);
    float4 sh0 = *(const float4*)(shift + c), sh1 = *(const float4*)(shift + c + 4);
    float4 o0, o1;
    o0.x = fmaxf(fmaf(bf2f((ushort)v[0]), sc0.x, sh0.x), 0.f);
    o0.y = fmaxf(fmaf(bf2f((ushort)v[1]), sc0.y, sh0.y), 0.f);
    o0.z = fmaxf(fmaf(bf2f((ushort)v[2]), sc0.z, sh0.z), 0.f);
    o0.w = fmaxf(fmaf(bf2f((ushort)v[3]), sc0.w, sh0.w), 0.f);
    o1.x = fmaxf(fmaf(bf2f((ushort)v[4]), sc1.x, sh1.x), 0.f);
    o1.y = fmaxf(fmaf(bf2f((ushort)v[5]), sc1.y, sh1.y), 0.f);
    o1.z = fmaxf(fmaf(bf2f((ushort)v[6]), sc1.z, sh1.z), 0.f);
    o1.w = fmaxf(fmaf(bf2f((ushort)v[7]), sc1.w, sh1.w), 0.f);
    ((float4*)out)[(size_t)i * 2]     = o0;
    ((float4*)out)[(size_t)i * 2 + 1] = o1;
}

// ================================================================
extern "C" void kernel_launch(void* const* d_in, const int* in_sizes, int n_in,
                              void* d_out, int out_size, void* d_ws, size_t ws_size,
                              hipStream_t stream) {
    const float* x      = (const float*)d_in[0];
    const int*   ei     = (const int*)d_in[1];
    const float* eps    = (const float*)d_in[3];
    const float* W1     = (const float*)d_in[4];
    const float* gamma1 = (const float*)d_in[5];
    const float* beta1  = (const float*)d_in[6];
    const float* W2     = (const float*)d_in[7];
    const float* gamma2 = (const float*)d_in[8];
    const float* beta2  = (const float*)d_in[9];
    int E = in_sizes[1] / 2;

    char* ws = (char*)d_ws;
    ushort* xB     = (ushort*)(ws);                 // 12,800,000 B (dead after gather)
    float*  partial= (float*)(ws);                  // 6,400,000 B  (overlaps xB; live from gemm1)
    ushort* hB     = (ushort*)(ws + 12800000);      // 12,800,000 B
    ushort* h1B    = (ushort*)(ws + 25600000);      // 25,600,000 B
    ushort* h2B    = (ushort*)(ws + 51200000);      // 25,600,000 B (overlaps bucket scratch)
    float*  stats  = (float*)(ws + 76800000);       // 4,096 B
    ushort* Wp1    = (ushort*)(ws + 76804096);      // 65,536 B
    ushort* Wp2    = (ushort*)(ws + 76869632);      // 131,072 B -> end 77,000,704
    float* scale1 = stats, *shift1 = stats + 256, *scale2 = stats + 512, *shift2 = stats + 768;
    float* out = (float*)d_out;

    // bucket scratch overlapping h2B (dead until gemm2)
    int*  bucket_fill = (int*)(ws + 51200000);              // 391*4 -> pad 2048
    uint* bucket_buf  = (uint*)(ws + 51202048);             // 391*3072*4 = 4,804,608 B

    hipMemsetAsync(bucket_fill, 0, NBKT * sizeof(int), stream);

    cvt_x_kernel<<<(800000 + 255) / 256, 256, 0, stream>>>(x, xB, 800000);
    pack_w_kernel<<<48, 256, 0, stream>>>(W1, W2, Wp1, Wp2);
    bucket_kernel<<<(E + EPB - 1) / EPB, 256, 0, stream>>>(ei, bucket_fill, bucket_buf, E);
    gather_bucket_kernel<<<NBKT, 512, 0, stream>>>(xB, eps, bucket_fill, bucket_buf, hB);

    gemm1_kernel<<<NB, 256, 0, stream>>>(hB, Wp1, h1B, partial);
    bn_finalize_kernel<<<D_H, 256, 0, stream>>>(partial, gamma1, beta1, scale1, shift1);
    gemm2_kernel<<<NB, 256, 0, stream>>>(h1B, Wp2, scale1, shift1, h2B, partial);
    bn_finalize_kernel<<<D_H, 256, 0, stream>>>(partial, gamma2, beta2, scale2, shift2);
    bn2_apply_kernel<<<(1600000 + 255) / 256, 256, 0, stream>>>(h2B, scale2, shift2, out, 1600000);
}